// Round 1
// baseline (1753.519 us; speedup 1.0000x reference)
//
#include <hip/hip_runtime.h>
#include <hip/hip_bf16.h>

// Int8Linear: out[M,N] = (x[M,K] fp32) x (w[N,K] int8-in-int32)^T * scale[N]
// M = 4*2048 = 8192, N = 11008, K = 4096.
// Strategy: cast x -> bf16 (RNE), w -> bf16 (exact, |w|<=128), fp32 MFMA
// accumulate (16x16x32 bf16), scale applied in fp32 epilogue.

#define M_DIM 8192
#define N_DIM 11008
#define K_DIM 4096

#define BM 128
#define BN 128
#define BK 32
#define LDK 40  // padded LDS row stride in bf16 elems (80 B -> bank spread)

using f32x4 = __attribute__((ext_vector_type(4))) float;
using i32x4 = __attribute__((ext_vector_type(4))) int;
using s16x4 = __attribute__((ext_vector_type(4))) short;
using s16x8 = __attribute__((ext_vector_type(8))) short;

__device__ __forceinline__ short cvt_bf16(float f) {
    union { float f; unsigned u; } v; v.f = f;
    unsigned r = v.u + 0x7fffu + ((v.u >> 16) & 1u);  // round-nearest-even
    return (short)(r >> 16);
}

__global__ __launch_bounds__(256) void int8_linear_gemm(
    const float* __restrict__ A,      // [M, K] fp32
    const int*   __restrict__ W,      // [N, K] int8-valued int32
    const float* __restrict__ scale,  // [N]
    float*       __restrict__ C)      // [M, N]
{
    __shared__ short As[BM][LDK];
    __shared__ short Bs[BN][LDK];

    const int tid = threadIdx.x;

    // GROUP_M=8 swizzle: 64 M-blocks x 86 N-blocks; keep 8 A-panels hot while
    // sweeping N so B re-reads come from L2/L3.
    const int bid = blockIdx.x;
    const int g   = bid / (8 * 86);
    const int rem = bid % (8 * 86);
    const int bm  = g * 8 + (rem & 7);
    const int bn  = rem >> 3;

    // staging: 256 threads, each loads 4x float4 (A) + 4x int4 (B) per K-step
    const int srow = tid >> 3;   // 0..31
    const int skq  = tid & 7;    // 0..7 (float4 column within BK=32)

    const float* Ab = A + (size_t)(bm * BM + srow) * K_DIM + skq * 4;
    const int*   Wb = W + (size_t)(bn * BN + srow) * K_DIM + skq * 4;

    const int lane = tid & 63;
    const int wave = tid >> 6;          // 0..3 -> 2x2 wave grid of 64x64 tiles
    const int wm   = (wave >> 1) * 64;
    const int wn   = (wave & 1) * 64;
    const int fr   = lane & 15;
    const int fq   = lane >> 4;

    f32x4 acc[4][4] = {};

    f32x4 areg[4];
    i32x4 breg[4];
    #pragma unroll
    for (int i = 0; i < 4; ++i) {
        areg[i] = *(const f32x4*)(Ab + (size_t)(i * 32) * K_DIM);
        breg[i] = *(const i32x4*)(Wb + (size_t)(i * 32) * K_DIM);
    }

    const int NT = K_DIM / BK;  // 128
    for (int kt = 0; kt < NT; ++kt) {
        __syncthreads();  // previous iteration's frag reads done
        #pragma unroll
        for (int i = 0; i < 4; ++i) {
            s16x4 av, bv;
            #pragma unroll
            for (int j = 0; j < 4; ++j) {
                av[j] = cvt_bf16(areg[i][j]);
                bv[j] = cvt_bf16((float)breg[i][j]);
            }
            *(s16x4*)&As[srow + i * 32][skq * 4] = av;
            *(s16x4*)&Bs[srow + i * 32][skq * 4] = bv;
        }
        __syncthreads();

        if (kt + 1 < NT) {  // issue next tile's loads; overlap with MFMA below
            const int k0 = (kt + 1) * BK;
            #pragma unroll
            for (int i = 0; i < 4; ++i) {
                areg[i] = *(const f32x4*)(Ab + (size_t)(i * 32) * K_DIM + k0);
                breg[i] = *(const i32x4*)(Wb + (size_t)(i * 32) * K_DIM + k0);
            }
        }

        s16x8 af[4], bf[4];
        #pragma unroll
        for (int m = 0; m < 4; ++m)
            af[m] = *(const s16x8*)&As[wm + m * 16 + fr][fq * 8];
        #pragma unroll
        for (int n = 0; n < 4; ++n)
            bf[n] = *(const s16x8*)&Bs[wn + n * 16 + fr][fq * 8];

        #pragma unroll
        for (int m = 0; m < 4; ++m)
            #pragma unroll
            for (int n = 0; n < 4; ++n)
                acc[m][n] = __builtin_amdgcn_mfma_f32_16x16x32_bf16(
                    af[m], bf[n], acc[m][n], 0, 0, 0);
    }

    // Epilogue: C[brow + m*16 + fq*4 + j][bcol + n*16 + fr] (m89-verified C/D map)
    #pragma unroll
    for (int n = 0; n < 4; ++n) {
        const int gn = bn * BN + wn + n * 16 + fr;
        const float s = scale[gn];
        #pragma unroll
        for (int m = 0; m < 4; ++m) {
            const int gm0 = bm * BM + wm + m * 16 + fq * 4;
            #pragma unroll
            for (int j = 0; j < 4; ++j) {
                C[(size_t)(gm0 + j) * N_DIM + gn] = acc[m][n][j] * s;
            }
        }
    }
}

extern "C" void kernel_launch(void* const* d_in, const int* in_sizes, int n_in,
                              void* d_out, int out_size, void* d_ws, size_t ws_size,
                              hipStream_t stream) {
    const float* x  = (const float*)d_in[0];
    const int*   w  = (const int*)d_in[1];
    const float* sc = (const float*)d_in[2];
    float* out = (float*)d_out;

    const int nblocks = (M_DIM / BM) * (N_DIM / BN);  // 64 * 86 = 5504
    int8_linear_gemm<<<dim3(nblocks), dim3(256), 0, stream>>>(x, w, sc, out);
}

// Round 2
// 1011.876 us; speedup vs baseline: 1.7329x; 1.7329x over previous
//
#include <hip/hip_runtime.h>
#include <hip/hip_bf16.h>

// Int8Linear: out[M,N] = (x[M,K] fp32) x (w[N,K] int8-in-int32)^T * scale[N]
// M = 8192, N = 11008, K = 4096.
// Round 2: prepass converts x->bf16 and w->bf16 into d_ws; GEMM is the m97
// structure (global_load_lds width-16, 128x128 tile, BK=32, 2-barrier loop)
// with fused per-column scale epilogue.

#define M_DIM 8192
#define N_DIM 11008
#define K_DIM 4096

#define BM 128
#define BN 128
#define BK 32

using f32x4 = __attribute__((ext_vector_type(4))) float;
using i32x4 = __attribute__((ext_vector_type(4))) int;
using s16x4 = __attribute__((ext_vector_type(4))) short;
using s16x8 = __attribute__((ext_vector_type(8))) short;

typedef __attribute__((address_space(3))) void lds_void_t;
typedef __attribute__((address_space(1))) const void gbl_void_t;

__device__ __forceinline__ short cvt_bf16(float f) {
    union { float f; unsigned u; } v; v.f = f;
    unsigned r = v.u + 0x7fffu + ((v.u >> 16) & 1u);  // round-nearest-even
    return (short)(r >> 16);
}

// ---- prepass: int32 weights -> bf16 (exact for |w| <= 128) ----
__global__ __launch_bounds__(256) void convert_w(const int* __restrict__ W,
                                                 short* __restrict__ Wb, int n4) {
    int i = blockIdx.x * blockDim.x + threadIdx.x;
    const int stride = gridDim.x * blockDim.x;
    for (; i < n4; i += stride) {
        i32x4 v = ((const i32x4*)W)[i];
        s16x4 o;
        #pragma unroll
        for (int j = 0; j < 4; ++j) o[j] = cvt_bf16((float)v[j]);
        ((s16x4*)Wb)[i] = o;
    }
}

// ---- prepass: fp32 x -> bf16 (RNE) ----
__global__ __launch_bounds__(256) void convert_x(const float* __restrict__ X,
                                                 short* __restrict__ Xb, int n4) {
    int i = blockIdx.x * blockDim.x + threadIdx.x;
    const int stride = gridDim.x * blockDim.x;
    for (; i < n4; i += stride) {
        f32x4 v = ((const f32x4*)X)[i];
        s16x4 o;
        #pragma unroll
        for (int j = 0; j < 4; ++j) o[j] = cvt_bf16(v[j]);
        ((s16x4*)Xb)[i] = o;
    }
}

// ---- main GEMM: bf16 x bf16^T, fp32 accum, scale epilogue ----
__global__ __launch_bounds__(256) void gemm_bf16(
    const short* __restrict__ A,      // [M, K] bf16
    const short* __restrict__ B,      // [N, K] bf16
    const float* __restrict__ scale,  // [N]
    float*       __restrict__ C)      // [M, N]
{
    // Linear LDS (NO padding: global_load_lds needs contiguous dest).
    // Row stride = BK = 32 elems = 64 B.
    __shared__ short As[BM * BK];
    __shared__ short Bs[BN * BK];

    const int tid = threadIdx.x;

    // XCD-chunked swizzle: 5504 blocks = 8 XCDs x 688. Each XCD owns one
    // GROUP_M=8 row-group and sweeps all 86 N-blocks (bm fastest).
    const int bid = blockIdx.x;
    const int wg  = (bid & 7) * 688 + (bid >> 3);
    const int g   = wg / (8 * 86);
    const int rem = wg % (8 * 86);
    const int bm  = g * 8 + (rem & 7);
    const int bn  = rem >> 3;

    // Staging: per K-step the A tile is 128x32 bf16 = 8192 B. 256 threads x
    // 16 B = 4096 B per global_load_lds instruction -> 2 instrs each for A,B.
    // LDS elem offset for instr i: i*2048 + tid*8  (linear, lane-ordered).
    // -> row = i*64 + tid/4, col = (tid&3)*8.
    const short* ag = A + (size_t)(bm * BM + (tid >> 2)) * K_DIM + (tid & 3) * 8;
    const short* bg = B + (size_t)(bn * BN + (tid >> 2)) * K_DIM + (tid & 3) * 8;

    lds_void_t* asl0 = (lds_void_t*)&As[tid * 8];
    lds_void_t* asl1 = (lds_void_t*)&As[2048 + tid * 8];
    lds_void_t* bsl0 = (lds_void_t*)&Bs[tid * 8];
    lds_void_t* bsl1 = (lds_void_t*)&Bs[2048 + tid * 8];

    const int lane = tid & 63;
    const int wave = tid >> 6;          // 2x2 wave grid of 64x64 tiles
    const int wm   = (wave >> 1) * 64;
    const int wn   = (wave & 1) * 64;
    const int fr   = lane & 15;
    const int fq   = lane >> 4;

    f32x4 acc[4][4] = {};

    const int NT = K_DIM / BK;  // 128
    for (int kt = 0; kt < NT; ++kt) {
        const int k0 = kt * BK;
        __builtin_amdgcn_global_load_lds((gbl_void_t*)(ag + k0),               asl0, 16, 0, 0);
        __builtin_amdgcn_global_load_lds((gbl_void_t*)(ag + k0 + 64 * K_DIM),  asl1, 16, 0, 0);
        __builtin_amdgcn_global_load_lds((gbl_void_t*)(bg + k0),               bsl0, 16, 0, 0);
        __builtin_amdgcn_global_load_lds((gbl_void_t*)(bg + k0 + 64 * K_DIM),  bsl1, 16, 0, 0);
        __syncthreads();  // compiler drains vmcnt before s_barrier

        s16x8 af[4], bf[4];
        #pragma unroll
        for (int m = 0; m < 4; ++m)
            af[m] = *(const s16x8*)&As[(wm + m * 16 + fr) * BK + fq * 8];
        #pragma unroll
        for (int n = 0; n < 4; ++n)
            bf[n] = *(const s16x8*)&Bs[(wn + n * 16 + fr) * BK + fq * 8];

        #pragma unroll
        for (int m = 0; m < 4; ++m)
            #pragma unroll
            for (int n = 0; n < 4; ++n)
                acc[m][n] = __builtin_amdgcn_mfma_f32_16x16x32_bf16(
                    af[m], bf[n], acc[m][n], 0, 0, 0);

        __syncthreads();  // frag reads done before next tile overwrites LDS
    }

    // Epilogue: C[bm*128 + wm + m*16 + fq*4 + j][bn*128 + wn + n*16 + fr] * scale
    #pragma unroll
    for (int n = 0; n < 4; ++n) {
        const int gn = bn * BN + wn + n * 16 + fr;
        const float s = scale[gn];
        #pragma unroll
        for (int m = 0; m < 4; ++m) {
            const int gm0 = bm * BM + wm + m * 16 + fq * 4;
            #pragma unroll
            for (int j = 0; j < 4; ++j) {
                C[(size_t)(gm0 + j) * N_DIM + gn] = acc[m][n][j] * s;
            }
        }
    }
}

// ---- fallback (round-1 fused kernel) if ws is too small ----
#define LDK 40
__global__ __launch_bounds__(256) void int8_linear_fused(
    const float* __restrict__ A, const int* __restrict__ W,
    const float* __restrict__ scale, float* __restrict__ C)
{
    __shared__ short As[BM][LDK];
    __shared__ short Bs[BN][LDK];
    const int tid = threadIdx.x;
    const int bid = blockIdx.x;
    const int g   = bid / (8 * 86);
    const int rem = bid % (8 * 86);
    const int bm  = g * 8 + (rem & 7);
    const int bn  = rem >> 3;
    const int srow = tid >> 3;
    const int skq  = tid & 7;
    const float* Ab = A + (size_t)(bm * BM + srow) * K_DIM + skq * 4;
    const int*   Wb = W + (size_t)(bn * BN + srow) * K_DIM + skq * 4;
    const int lane = tid & 63, wave = tid >> 6;
    const int wm = (wave >> 1) * 64, wn = (wave & 1) * 64;
    const int fr = lane & 15, fq = lane >> 4;
    f32x4 acc[4][4] = {};
    f32x4 areg[4]; i32x4 breg[4];
    #pragma unroll
    for (int i = 0; i < 4; ++i) {
        areg[i] = *(const f32x4*)(Ab + (size_t)(i * 32) * K_DIM);
        breg[i] = *(const i32x4*)(Wb + (size_t)(i * 32) * K_DIM);
    }
    const int NT = K_DIM / BK;
    for (int kt = 0; kt < NT; ++kt) {
        __syncthreads();
        #pragma unroll
        for (int i = 0; i < 4; ++i) {
            s16x4 av, bv;
            #pragma unroll
            for (int j = 0; j < 4; ++j) {
                av[j] = cvt_bf16(areg[i][j]);
                bv[j] = cvt_bf16((float)breg[i][j]);
            }
            *(s16x4*)&As[srow + i * 32][skq * 4] = av;
            *(s16x4*)&Bs[srow + i * 32][skq * 4] = bv;
        }
        __syncthreads();
        if (kt + 1 < NT) {
            const int k0 = (kt + 1) * BK;
            #pragma unroll
            for (int i = 0; i < 4; ++i) {
                areg[i] = *(const f32x4*)(Ab + (size_t)(i * 32) * K_DIM + k0);
                breg[i] = *(const i32x4*)(Wb + (size_t)(i * 32) * K_DIM + k0);
            }
        }
        s16x8 af[4], bf[4];
        #pragma unroll
        for (int m = 0; m < 4; ++m) af[m] = *(const s16x8*)&As[wm + m * 16 + fr][fq * 8];
        #pragma unroll
        for (int n = 0; n < 4; ++n) bf[n] = *(const s16x8*)&Bs[wn + n * 16 + fr][fq * 8];
        #pragma unroll
        for (int m = 0; m < 4; ++m)
            #pragma unroll
            for (int n = 0; n < 4; ++n)
                acc[m][n] = __builtin_amdgcn_mfma_f32_16x16x32_bf16(af[m], bf[n], acc[m][n], 0, 0, 0);
    }
    #pragma unroll
    for (int n = 0; n < 4; ++n) {
        const int gn = bn * BN + wn + n * 16 + fr;
        const float s = scale[gn];
        #pragma unroll
        for (int m = 0; m < 4; ++m) {
            const int gm0 = bm * BM + wm + m * 16 + fq * 4;
            #pragma unroll
            for (int j = 0; j < 4; ++j)
                C[(size_t)(gm0 + j) * N_DIM + gn] = acc[m][n][j] * s;
        }
    }
}

extern "C" void kernel_launch(void* const* d_in, const int* in_sizes, int n_in,
                              void* d_out, int out_size, void* d_ws, size_t ws_size,
                              hipStream_t stream) {
    const float* x  = (const float*)d_in[0];
    const int*   w  = (const int*)d_in[1];
    const float* sc = (const float*)d_in[2];
    float* out = (float*)d_out;

    const size_t w_elems = (size_t)N_DIM * K_DIM;   // 45,088,768
    const size_t x_elems = (size_t)M_DIM * K_DIM;   // 33,554,432
    const size_t need = (w_elems + x_elems) * sizeof(short);  // ~157 MB

    const int nblocks = (M_DIM / BM) * (N_DIM / BN);  // 5504

    if (ws_size >= need) {
        short* wb = (short*)d_ws;
        short* xb = wb + w_elems;
        convert_w<<<dim3(2048), dim3(256), 0, stream>>>(w, wb, (int)(w_elems / 4));
        convert_x<<<dim3(2048), dim3(256), 0, stream>>>(x, xb, (int)(x_elems / 4));
        gemm_bf16<<<dim3(nblocks), dim3(256), 0, stream>>>(xb, wb, sc, out);
    } else {
        int8_linear_fused<<<dim3(nblocks), dim3(256), 0, stream>>>(x, w, sc, out);
    }
}

// Round 3
// 791.644 us; speedup vs baseline: 2.2150x; 1.2782x over previous
//
#include <hip/hip_runtime.h>
#include <hip/hip_bf16.h>

// Int8Linear: out[M,N] = (x[M,K] fp32) x (w[N,K] int8-in-int32)^T * scale[N]
// Round 3: prepass (x,w -> bf16 in d_ws) + 256x256 8-phase GEMM (T1+T2+T3+T4+T5):
//   - BK=64, 512 thr / 8 waves (2M x 4N), per-wave 128x64 out, acc[8][4]
//   - double-buffered LDS 128 KB, global_load_lds width-16 direct staging
//   - XOR bank swizzle (chunk ^= row&7): pre-swizzled GLOBAL source, swizzled ds_read
//   - Gray-code quadrant phases, counted vmcnt(4) once per K-tile, raw s_barrier
//   - setprio(1) around MFMA clusters

#define M_DIM 8192
#define N_DIM 11008
#define K_DIM 4096

#define BM 256
#define BN 256
#define BK 64
#define NKT (K_DIM / BK)  // 64 K-tiles, 32 iterations of 2

using f32x4 = __attribute__((ext_vector_type(4))) float;
using i32x4 = __attribute__((ext_vector_type(4))) int;
using s16x4 = __attribute__((ext_vector_type(4))) short;
using s16x8 = __attribute__((ext_vector_type(8))) short;

typedef __attribute__((address_space(3))) void lds_void_t;
typedef __attribute__((address_space(1))) const void gbl_void_t;

__device__ __forceinline__ short cvt_bf16(float f) {
    union { float f; unsigned u; } v; v.f = f;
    unsigned r = v.u + 0x7fffu + ((v.u >> 16) & 1u);  // RNE
    return (short)(r >> 16);
}

__global__ __launch_bounds__(256) void convert_w(const int* __restrict__ W,
                                                 short* __restrict__ Wb, int n4) {
    int i = blockIdx.x * blockDim.x + threadIdx.x;
    const int stride = gridDim.x * blockDim.x;
    for (; i < n4; i += stride) {
        i32x4 v = ((const i32x4*)W)[i];
        s16x4 o;
        #pragma unroll
        for (int j = 0; j < 4; ++j) o[j] = cvt_bf16((float)v[j]);
        ((s16x4*)Wb)[i] = o;
    }
}

__global__ __launch_bounds__(256) void convert_x(const float* __restrict__ X,
                                                 short* __restrict__ Xb, int n4) {
    int i = blockIdx.x * blockDim.x + threadIdx.x;
    const int stride = gridDim.x * blockDim.x;
    for (; i < n4; i += stride) {
        f32x4 v = ((const f32x4*)X)[i];
        s16x4 o;
        #pragma unroll
        for (int j = 0; j < 4; ++j) o[j] = cvt_bf16(v[j]);
        ((s16x4*)Xb)[i] = o;
    }
}

#define SBAR __builtin_amdgcn_s_barrier()
#define WAIT_LGKM do { asm volatile("s_waitcnt lgkmcnt(0)" ::: "memory"); \
                       __builtin_amdgcn_sched_barrier(0); } while (0)
#define WAIT_VM(n) asm volatile("s_waitcnt vmcnt(" #n ")" ::: "memory")

// Stage one full operand tile (256x64 bf16 = 32 KB) of tile T: 4 gload_lds x 512 thr.
// LDS dest is LINEAR (chunk c = _i*512+tid); bank swizzle achieved by pre-swizzling
// the global source column chunk: jl = (tid&7) ^ ((tid>>3)&7)  (invariant over _i
// since _i*64 == 0 mod 8).
#define STAGE(bufi, opi, srcp, toff) do {                                          \
    short* _d = &lds[bufi][opi][0][0];                                             \
    _Pragma("unroll")                                                              \
    for (int _i = 0; _i < 4; ++_i)                                                 \
        __builtin_amdgcn_global_load_lds(                                          \
            (gbl_void_t*)((srcp) + (size_t)_i * 64 * K_DIM + (toff)),              \
            (lds_void_t*)(_d + (_i * 512 + tid) * 8), 16, 0, 0);                   \
} while (0)

// Read A quadrant qm (4 m-frags x 2 k-steps = 8 x ds_read_b128), swizzled.
// elem offset = row*64 + (colchunk ^ fr7)*8, row = qm*64 + m*16 + fr (row&7 == fr&7).
#define READ_A(dst, bufi, qm) do {                                                 \
    const short* _s = &lds[bufi][0][mi][0];                                        \
    _Pragma("unroll")                                                              \
    for (int _m = 0; _m < 4; ++_m)                                                 \
        _Pragma("unroll")                                                          \
        for (int _k = 0; _k < 2; ++_k)                                             \
            dst[_m][_k] = *(const s16x8*)(_s + ((qm) * 64 + _m * 16 + fr) * 64     \
                                          + ((((_k << 2) | fq) ^ fr7) << 3));      \
} while (0)

// Read B quadrant qn (2 n-frags x 2 k-steps = 4 x ds_read_b128), swizzled.
#define READ_B(dst, bufi, qn) do {                                                 \
    const short* _s = &lds[bufi][1][ni >> 1][0];                                   \
    _Pragma("unroll")                                                              \
    for (int _n = 0; _n < 2; ++_n)                                                 \
        _Pragma("unroll")                                                          \
        for (int _k = 0; _k < 2; ++_k)                                             \
            dst[_n][_k] = *(const s16x8*)(_s + ((ni & 1) * 64 + (qn) * 32          \
                                          + _n * 16 + fr) * 64                     \
                                          + ((((_k << 2) | fq) ^ fr7) << 3));      \
} while (0)

#define MFMA_Q(qm, qn, aset, bset) do {                                            \
    __builtin_amdgcn_s_setprio(1);                                                 \
    _Pragma("unroll")                                                              \
    for (int _m = 0; _m < 4; ++_m)                                                 \
        _Pragma("unroll")                                                          \
        for (int _n = 0; _n < 2; ++_n)                                             \
            _Pragma("unroll")                                                      \
            for (int _k = 0; _k < 2; ++_k)                                         \
                acc[(qm) * 4 + _m][(qn) * 2 + _n] =                                \
                    __builtin_amdgcn_mfma_f32_16x16x32_bf16(                       \
                        aset[_m][_k], bset[_n][_k],                                \
                        acc[(qm) * 4 + _m][(qn) * 2 + _n], 0, 0, 0);               \
    __builtin_amdgcn_s_setprio(0);                                                 \
} while (0)

// One half-iteration: compute K-tile T from buf BUF; read tile T+1 frags from OBUF;
// stage tile T+2 into BUF. BQ0 holds B(T,qn0) on entry; BQ1 receives B(T+1,qn0).
// Slot safety: BUF.B last read ph1 -> staged ph2; BUF.A last read ph2 -> staged ph3.
// vmcnt(4) at ph3 drains tile T+1 (leaves B(T+2) in flight).
#define HALF_ITER(BUF, OBUF, BQ0, BQ1, T) do {                                     \
    /* ph1 */ READ_B(BQ1, BUF, 1);                                                 \
    SBAR; WAIT_LGKM; MFMA_Q(0, 0, a0, BQ0); SBAR;                                  \
    /* ph2 */ READ_A(a1, BUF, 1); STAGE(BUF, 1, Bsrc, (size_t)(((T)+2) & 63) * 64);\
    SBAR; WAIT_LGKM; MFMA_Q(0, 1, a0, BQ1); SBAR;                                  \
    /* ph3 */ WAIT_VM(4);                                                          \
    READ_A(a0, OBUF, 0); STAGE(BUF, 0, Asrc, (size_t)(((T)+2) & 63) * 64);         \
    SBAR; WAIT_LGKM; MFMA_Q(1, 1, a1, BQ1); SBAR;                                  \
    /* ph4 */ READ_B(BQ1, OBUF, 0);                                                \
    SBAR; WAIT_LGKM; MFMA_Q(1, 0, a1, BQ0); SBAR;                                  \
} while (0)

__global__ __launch_bounds__(512, 2) void gemm_bf16_8ph(
    const short* __restrict__ A,      // [M, K] bf16
    const short* __restrict__ B,      // [N, K] bf16
    const float* __restrict__ scale,  // [N]
    float*       __restrict__ C)      // [M, N]
{
    // [buf][A=0/B=1][half][128 rows * 64 cols] = 128 KiB
    __shared__ __align__(16) short lds[2][2][2][128 * 64];

    const int tid  = threadIdx.x;
    const int lane = tid & 63;
    const int fr   = lane & 15;
    const int fq   = lane >> 4;
    const int fr7  = fr & 7;
    const int wave = tid >> 6;
    const int mi   = wave >> 2;   // 0..1: A half (128-row block)
    const int ni   = wave & 3;    // 0..3: 64-col block

    // XCD-chunked bijective swizzle: 1376 = 8 x 172; per XCD: 4 bm x 43 bn, bm fastest.
    const int bid = blockIdx.x;
    const int xcd = bid & 7;
    const int idx = bid >> 3;             // 0..171
    const int bm  = xcd * 4 + (idx & 3);  // 0..31
    const int bn  = idx >> 2;             // 0..42

    // Per-thread pre-swizzled staging source (elements). chunk c = i*512+tid:
    // row = i*64 + (tid>>3), src colchunk = (tid&7) ^ (row&7) = (tid&7)^((tid>>3)&7).
    const int jl   = (tid & 7) ^ ((tid >> 3) & 7);
    const int soff = (tid >> 3) * K_DIM + jl * 8;
    const short* Asrc = A + (size_t)bm * BM * K_DIM + soff;
    const short* Bsrc = B + (size_t)bn * BN * K_DIM + soff;

    f32x4 acc[8][4] = {};
    s16x8 a0[4][2], a1[4][2], b_a[2][2], b_b[2][2];

    // Prologue: stage tiles 0 (buf0) and 1 (buf1); drain tile0; pre-read its
    // first quadrant frags (the "ph3/ph4 of iteration -1").
    STAGE(0, 1, Bsrc, 0);
    STAGE(0, 0, Asrc, 0);
    STAGE(1, 1, Bsrc, 64);
    STAGE(1, 0, Asrc, 64);
    WAIT_VM(8);
    SBAR;
    READ_A(a0, 0, 0);   // A(0, qm0)
    READ_B(b_a, 0, 0);  // B(0, qn0)

    for (int it = 0; it < 32; ++it) {
        const int t0 = 2 * it;
        HALF_ITER(0, 1, b_a, b_b, t0);      // tile t0   (buf0)
        HALF_ITER(1, 0, b_b, b_a, t0 + 1);  // tile t0+1 (buf1)
    }

    // Epilogue: acc[i][jn][jj] -> C[row0 + i*16 + jj][col0 + jn*16] * scale
    const int row0 = bm * BM + mi * 128 + fq * 4;
    const int col0 = bn * BN + ni * 64 + fr;
    float s4[4];
    #pragma unroll
    for (int jn = 0; jn < 4; ++jn) s4[jn] = scale[col0 + jn * 16];
    #pragma unroll
    for (int i = 0; i < 8; ++i)
        #pragma unroll
        for (int jn = 0; jn < 4; ++jn)
            #pragma unroll
            for (int jj = 0; jj < 4; ++jj)
                C[(size_t)(row0 + i * 16 + jj) * N_DIM + col0 + jn * 16] =
                    acc[i][jn][jj] * s4[jn];
}

// ---- fallback (round-1 fused kernel) if ws is too small ----
#define FBM 128
#define FBN 128
#define FBK 32
#define LDK 40
__global__ __launch_bounds__(256) void int8_linear_fused(
    const float* __restrict__ A, const int* __restrict__ W,
    const float* __restrict__ scale, float* __restrict__ C)
{
    __shared__ short As[FBM][LDK];
    __shared__ short Bs[FBN][LDK];
    const int tid = threadIdx.x;
    const int bid = blockIdx.x;
    const int g   = bid / (8 * 86);
    const int rem = bid % (8 * 86);
    const int bm  = g * 8 + (rem & 7);
    const int bn  = rem >> 3;
    const int srow = tid >> 3;
    const int skq  = tid & 7;
    const float* Ab = A + (size_t)(bm * FBM + srow) * K_DIM + skq * 4;
    const int*   Wb = W + (size_t)(bn * FBN + srow) * K_DIM + skq * 4;
    const int lane = tid & 63, wave = tid >> 6;
    const int wm = (wave >> 1) * 64, wn = (wave & 1) * 64;
    const int fr = lane & 15, fq = lane >> 4;
    f32x4 acc[4][4] = {};
    f32x4 areg[4]; i32x4 breg[4];
    #pragma unroll
    for (int i = 0; i < 4; ++i) {
        areg[i] = *(const f32x4*)(Ab + (size_t)(i * 32) * K_DIM);
        breg[i] = *(const i32x4*)(Wb + (size_t)(i * 32) * K_DIM);
    }
    const int NT = K_DIM / FBK;
    for (int kt = 0; kt < NT; ++kt) {
        __syncthreads();
        #pragma unroll
        for (int i = 0; i < 4; ++i) {
            s16x4 av, bv;
            #pragma unroll
            for (int j = 0; j < 4; ++j) {
                av[j] = cvt_bf16(areg[i][j]);
                bv[j] = cvt_bf16((float)breg[i][j]);
            }
            *(s16x4*)&As[srow + i * 32][skq * 4] = av;
            *(s16x4*)&Bs[srow + i * 32][skq * 4] = bv;
        }
        __syncthreads();
        if (kt + 1 < NT) {
            const int k0 = (kt + 1) * FBK;
            #pragma unroll
            for (int i = 0; i < 4; ++i) {
                areg[i] = *(const f32x4*)(Ab + (size_t)(i * 32) * K_DIM + k0);
                breg[i] = *(const i32x4*)(Wb + (size_t)(i * 32) * K_DIM + k0);
            }
        }
        s16x8 af[4], bf[4];
        #pragma unroll
        for (int m = 0; m < 4; ++m) af[m] = *(const s16x8*)&As[wm + m * 16 + fr][fq * 8];
        #pragma unroll
        for (int n = 0; n < 4; ++n) bf[n] = *(const s16x8*)&Bs[wn + n * 16 + fr][fq * 8];
        #pragma unroll
        for (int m = 0; m < 4; ++m)
            #pragma unroll
            for (int n = 0; n < 4; ++n)
                acc[m][n] = __builtin_amdgcn_mfma_f32_16x16x32_bf16(af[m], bf[n], acc[m][n], 0, 0, 0);
    }
    #pragma unroll
    for (int n = 0; n < 4; ++n) {
        const int gn = bn * FBN + wn + n * 16 + fr;
        const float s = scale[gn];
        #pragma unroll
        for (int m = 0; m < 4; ++m) {
            const int gm0 = bm * FBM + wm + m * 16 + fq * 4;
            #pragma unroll
            for (int j = 0; j < 4; ++j)
                C[(size_t)(gm0 + j) * N_DIM + gn] = acc[m][n][j] * s;
        }
    }
}

extern "C" void kernel_launch(void* const* d_in, const int* in_sizes, int n_in,
                              void* d_out, int out_size, void* d_ws, size_t ws_size,
                              hipStream_t stream) {
    const float* x  = (const float*)d_in[0];
    const int*   w  = (const int*)d_in[1];
    const float* sc = (const float*)d_in[2];
    float* out = (float*)d_out;

    const size_t w_elems = (size_t)N_DIM * K_DIM;
    const size_t x_elems = (size_t)M_DIM * K_DIM;
    const size_t need = (w_elems + x_elems) * sizeof(short);

    if (ws_size >= need) {
        short* wb = (short*)d_ws;
        short* xb = wb + w_elems;
        convert_w<<<dim3(2048), dim3(256), 0, stream>>>(w, wb, (int)(w_elems / 4));
        convert_x<<<dim3(2048), dim3(256), 0, stream>>>(x, xb, (int)(x_elems / 4));
        const int nblocks = (M_DIM / BM) * (N_DIM / BN);  // 32 * 43 = 1376
        gemm_bf16_8ph<<<dim3(nblocks), dim3(512), 0, stream>>>(xb, wb, sc, out);
    } else {
        const int nblocks = (M_DIM / FBM) * (N_DIM / FBN);
        int8_linear_fused<<<dim3(nblocks), dim3(256), 0, stream>>>(x, w, sc, out);
    }
}

// Round 4
// 720.861 us; speedup vs baseline: 2.4325x; 1.0982x over previous
//
#include <hip/hip_runtime.h>
#include <hip/hip_bf16.h>

// Int8Linear: out[M,N] = (x[M,K] fp32) x (w[N,K] int8-in-int32)^T * scale[N]
// Round 4: same 256x256/BK=64/8-wave geometry as round 3, but re-scheduled:
//   - ONE barrier per phase (4/tile, was 8)
//   - read-lookahead: phase p issues READ(p+1), waits COUNTED lgkmcnt(n_next)
//     so LDS reads for p+1 execute under MFMA(p)  (m201's 4/8/0/12 pattern)
//   - vmcnt(4) at end of p3 BEFORE the barrier (fixes round-3 cross-wave race)
//   - nontemporal C stores (keep bf16 inputs L3-resident vs 360 MB C stream)

#define M_DIM 8192
#define N_DIM 11008
#define K_DIM 4096

#define BM 256
#define BN 256
#define BK 64

using f32x4 = __attribute__((ext_vector_type(4))) float;
using i32x4 = __attribute__((ext_vector_type(4))) int;
using s16x4 = __attribute__((ext_vector_type(4))) short;
using s16x8 = __attribute__((ext_vector_type(8))) short;

typedef __attribute__((address_space(3))) void lds_void_t;
typedef __attribute__((address_space(1))) const void gbl_void_t;

__device__ __forceinline__ short cvt_bf16(float f) {
    union { float f; unsigned u; } v; v.f = f;
    unsigned r = v.u + 0x7fffu + ((v.u >> 16) & 1u);  // RNE
    return (short)(r >> 16);
}

__global__ __launch_bounds__(256) void convert_w(const int* __restrict__ W,
                                                 short* __restrict__ Wb, int n4) {
    int i = blockIdx.x * blockDim.x + threadIdx.x;
    const int stride = gridDim.x * blockDim.x;
    for (; i < n4; i += stride) {
        i32x4 v = ((const i32x4*)W)[i];
        s16x4 o;
        #pragma unroll
        for (int j = 0; j < 4; ++j) o[j] = cvt_bf16((float)v[j]);
        ((s16x4*)Wb)[i] = o;
    }
}

__global__ __launch_bounds__(256) void convert_x(const float* __restrict__ X,
                                                 short* __restrict__ Xb, int n4) {
    int i = blockIdx.x * blockDim.x + threadIdx.x;
    const int stride = gridDim.x * blockDim.x;
    for (; i < n4; i += stride) {
        f32x4 v = ((const f32x4*)X)[i];
        s16x4 o;
        #pragma unroll
        for (int j = 0; j < 4; ++j) o[j] = cvt_bf16(v[j]);
        ((s16x4*)Xb)[i] = o;
    }
}

#define SBAR __builtin_amdgcn_s_barrier()
// Counted LDS wait + scheduler fence (rule #18: pin MFMA below the wait).
#define LGKM(n) do { asm volatile("s_waitcnt lgkmcnt(" #n ")" ::: "memory"); \
                     __builtin_amdgcn_sched_barrier(0); } while (0)
#define WAIT_VM(n) do { asm volatile("s_waitcnt vmcnt(" #n ")" ::: "memory"); \
                        __builtin_amdgcn_sched_barrier(0); } while (0)

// Stage one operand tile (256x64 bf16 = 32 KB): 4 gload_lds x 512 thr.
// LDS dest LINEAR; bank swizzle via pre-swizzled global source column.
#define STAGE(bufi, opi, srcp, T) do {                                             \
    short* _d = &lds[bufi][opi][0][0];                                             \
    const size_t _toff = (size_t)((T) & 63) * 64;                                  \
    _Pragma("unroll")                                                              \
    for (int _i = 0; _i < 4; ++_i)                                                 \
        __builtin_amdgcn_global_load_lds(                                          \
            (gbl_void_t*)((srcp) + (size_t)_i * 64 * K_DIM + _toff),               \
            (lds_void_t*)(_d + (_i * 512 + tid) * 8), 16, 0, 0);                   \
} while (0)

// Read A quadrant qm (8 x ds_read_b128), swizzled (row&7 == fr&7).
#define READ_A(dst, bufi, qm) do {                                                 \
    const short* _s = &lds[bufi][0][mi][0];                                        \
    _Pragma("unroll")                                                              \
    for (int _m = 0; _m < 4; ++_m)                                                 \
        _Pragma("unroll")                                                          \
        for (int _k = 0; _k < 2; ++_k)                                             \
            dst[_m][_k] = *(const s16x8*)(_s + ((qm) * 64 + _m * 16 + fr) * 64     \
                                          + ((((_k << 2) | fq) ^ fr7) << 3));      \
} while (0)

// Read B quadrant qn (4 x ds_read_b128), swizzled.
#define READ_B(dst, bufi, qn) do {                                                 \
    const short* _s = &lds[bufi][1][ni >> 1][0];                                   \
    _Pragma("unroll")                                                              \
    for (int _n = 0; _n < 2; ++_n)                                                 \
        _Pragma("unroll")                                                          \
        for (int _k = 0; _k < 2; ++_k)                                             \
            dst[_n][_k] = *(const s16x8*)(_s + ((ni & 1) * 64 + (qn) * 32          \
                                          + _n * 16 + fr) * 64                     \
                                          + ((((_k << 2) | fq) ^ fr7) << 3));      \
} while (0)

#define MFMA_Q(qm, qn, aset, bset) do {                                            \
    __builtin_amdgcn_s_setprio(1);                                                 \
    _Pragma("unroll")                                                              \
    for (int _m = 0; _m < 4; ++_m)                                                 \
        _Pragma("unroll")                                                          \
        for (int _n = 0; _n < 2; ++_n)                                             \
            _Pragma("unroll")                                                      \
            for (int _k = 0; _k < 2; ++_k)                                         \
                acc[(qm) * 4 + _m][(qn) * 2 + _n] =                                \
                    __builtin_amdgcn_mfma_f32_16x16x32_bf16(                       \
                        aset[_m][_k], bset[_n][_k],                                \
                        acc[(qm) * 4 + _m][(qn) * 2 + _n], 0, 0, 0);               \
    __builtin_amdgcn_s_setprio(0);                                                 \
} while (0)

// Tile T in BUF (other buffer OBUF holds T+1). BQ0 = b0(T) regs, BQ1 receives
// b1(T) then b0(T+1). a0 holds a0(T) on entry (loaded at p4 of T-1).
// Reads/phase: p1:4  p2:8  p3:0  p4:12.  Stages: B(T+2)@p3, A(T+2)@p4.
// Region safety (1 barrier/phase): a region is staged only in the phase AFTER
// all waves counted-lgkm'd its last reads (pre-barrier) — B: reads p4(T-1)/p1,
// covered p2 -> stage p3.  A: reads p4(T-1)/p2, covered p3 -> stage p4.
// vmcnt(4) end-of-p3 pre-barrier => at p4 every wave sees T+1 fully landed.
#define HALF_ITER(BUF, OBUF, BQ0, BQ1, T) do {                                     \
    /* p1: MFMA(q00) a0*BQ0 ; lookahead b1(T) */                                   \
    READ_B(BQ1, BUF, 1);                                                           \
    LGKM(4);                                                                       \
    MFMA_Q(0, 0, a0, BQ0);                                                         \
    SBAR;                                                                          \
    /* p2: MFMA(q01) a0*BQ1 ; lookahead a1(T) */                                   \
    READ_A(a1, BUF, 1);                                                            \
    LGKM(8);                                                                       \
    MFMA_Q(0, 1, a0, BQ1);                                                         \
    SBAR;                                                                          \
    /* p3: MFMA(q11) a1*BQ1 ; stage B(T+2); drain T+1 pre-barrier */               \
    STAGE(BUF, 1, Bsrc, (T) + 2);                                                  \
    LGKM(0);                                                                       \
    MFMA_Q(1, 1, a1, BQ1);                                                         \
    WAIT_VM(4);                                                                    \
    SBAR;                                                                          \
    /* p4: MFMA(q10) a1*BQ0 ; stage A(T+2); lookahead a0,b0(T+1) from OBUF */      \
    STAGE(BUF, 0, Asrc, (T) + 2);                                                  \
    READ_A(a0, OBUF, 0);                                                           \
    READ_B(BQ1, OBUF, 0);                                                          \
    LGKM(12);                                                                      \
    MFMA_Q(1, 0, a1, BQ0);                                                         \
    SBAR;                                                                          \
} while (0)

__global__ __launch_bounds__(512, 2) void gemm_bf16_8ph(
    const short* __restrict__ A,      // [M, K] bf16
    const short* __restrict__ B,      // [N, K] bf16
    const float* __restrict__ scale,  // [N]
    float*       __restrict__ C)      // [M, N]
{
    __shared__ __align__(16) short lds[2][2][2][128 * 64];  // 128 KiB

    const int tid  = threadIdx.x;
    const int lane = tid & 63;
    const int fr   = lane & 15;
    const int fq   = lane >> 4;
    const int fr7  = fr & 7;
    const int wave = tid >> 6;
    const int mi   = wave >> 2;   // 0..1: A half (128-row block)
    const int ni   = wave & 3;    // 0..3: 64-col block

    // XCD-chunked bijective swizzle: 1376 = 8 x 172; per XCD: 4 bm x 43 bn.
    const int bid = blockIdx.x;
    const int xcd = bid & 7;
    const int idx = bid >> 3;             // 0..171
    const int bm  = xcd * 4 + (idx & 3);  // 0..31
    const int bn  = idx >> 2;             // 0..42

    // Pre-swizzled staging source: chunk c = i*512+tid -> row = i*64+(tid>>3),
    // src colchunk = (tid&7) ^ (row&7) = (tid&7) ^ ((tid>>3)&7).
    const int jl   = (tid & 7) ^ ((tid >> 3) & 7);
    const int soff = (tid >> 3) * K_DIM + jl * 8;
    const short* Asrc = A + (size_t)bm * BM * K_DIM + soff;
    const short* Bsrc = B + (size_t)bn * BN * K_DIM + soff;

    f32x4 acc[8][4] = {};
    s16x8 a0[4][2], a1[4][2], b_a[2][2], b_b[2][2];

    // Prologue: stage tiles 0 (buf0) and 1 (buf1); drain tile0 across all
    // waves (vmcnt pre-barrier); pre-read tile0's first-quadrant frags.
    STAGE(0, 1, Bsrc, 0);
    STAGE(0, 0, Asrc, 0);
    STAGE(1, 1, Bsrc, 1);
    STAGE(1, 0, Asrc, 1);
    WAIT_VM(8);
    SBAR;
    READ_A(a0, 0, 0);   // 12 ds_reads outstanding entering p1 (drained by LGKM(4))
    READ_B(b_a, 0, 0);

    for (int it = 0; it < 32; ++it) {
        const int t0 = 2 * it;
        HALF_ITER(0, 1, b_a, b_b, t0);      // tile t0   (buf0)
        HALF_ITER(1, 0, b_b, b_a, t0 + 1);  // tile t0+1 (buf1)
    }

    // Epilogue: nontemporal C stores (C streams once; keep inputs in L3).
    const int row0 = bm * BM + mi * 128 + fq * 4;
    const int col0 = bn * BN + ni * 64 + fr;
    float s4[4];
    #pragma unroll
    for (int jn = 0; jn < 4; ++jn) s4[jn] = scale[col0 + jn * 16];
    #pragma unroll
    for (int i = 0; i < 8; ++i)
        #pragma unroll
        for (int jn = 0; jn < 4; ++jn)
            #pragma unroll
            for (int jj = 0; jj < 4; ++jj)
                __builtin_nontemporal_store(
                    acc[i][jn][jj] * s4[jn],
                    &C[(size_t)(row0 + i * 16 + jj) * N_DIM + col0 + jn * 16]);
}

// ---- fallback (round-1 fused kernel) if ws is too small ----
#define FBM 128
#define FBN 128
#define FBK 32
#define LDK 40
__global__ __launch_bounds__(256) void int8_linear_fused(
    const float* __restrict__ A, const int* __restrict__ W,
    const float* __restrict__ scale, float* __restrict__ C)
{
    __shared__ short As[FBM][LDK];
    __shared__ short Bs[FBN][LDK];
    const int tid = threadIdx.x;
    const int bid = blockIdx.x;
    const int g   = bid / (8 * 86);
    const int rem = bid % (8 * 86);
    const int bm  = g * 8 + (rem & 7);
    const int bn  = rem >> 3;
    const int srow = tid >> 3;
    const int skq  = tid & 7;
    const float* Ab = A + (size_t)(bm * FBM + srow) * K_DIM + skq * 4;
    const int*   Wb = W + (size_t)(bn * FBN + srow) * K_DIM + skq * 4;
    const int lane = tid & 63, wave = tid >> 6;
    const int wm = (wave >> 1) * 64, wn = (wave & 1) * 64;
    const int fr = lane & 15, fq = lane >> 4;
    f32x4 acc[4][4] = {};
    f32x4 areg[4]; i32x4 breg[4];
    #pragma unroll
    for (int i = 0; i < 4; ++i) {
        areg[i] = *(const f32x4*)(Ab + (size_t)(i * 32) * K_DIM);
        breg[i] = *(const i32x4*)(Wb + (size_t)(i * 32) * K_DIM);
    }
    const int NT = K_DIM / FBK;
    for (int kt = 0; kt < NT; ++kt) {
        __syncthreads();
        #pragma unroll
        for (int i = 0; i < 4; ++i) {
            s16x4 av, bv;
            #pragma unroll
            for (int j = 0; j < 4; ++j) {
                av[j] = cvt_bf16(areg[i][j]);
                bv[j] = cvt_bf16((float)breg[i][j]);
            }
            *(s16x4*)&As[srow + i * 32][skq * 4] = av;
            *(s16x4*)&Bs[srow + i * 32][skq * 4] = bv;
        }
        __syncthreads();
        if (kt + 1 < NT) {
            const int k0 = (kt + 1) * FBK;
            #pragma unroll
            for (int i = 0; i < 4; ++i) {
                areg[i] = *(const f32x4*)(Ab + (size_t)(i * 32) * K_DIM + k0);
                breg[i] = *(const i32x4*)(Wb + (size_t)(i * 32) * K_DIM + k0);
            }
        }
        s16x8 af[4], bf[4];
        #pragma unroll
        for (int m = 0; m < 4; ++m) af[m] = *(const s16x8*)&As[wm + m * 16 + fr][fq * 8];
        #pragma unroll
        for (int n = 0; n < 4; ++n) bf[n] = *(const s16x8*)&Bs[wn + n * 16 + fr][fq * 8];
        #pragma unroll
        for (int m = 0; m < 4; ++m)
            #pragma unroll
            for (int n = 0; n < 4; ++n)
                acc[m][n] = __builtin_amdgcn_mfma_f32_16x16x32_bf16(af[m], bf[n], acc[m][n], 0, 0, 0);
    }
    #pragma unroll
    for (int n = 0; n < 4; ++n) {
        const int gn = bn * FBN + wn + n * 16 + fr;
        const float s = scale[gn];
        #pragma unroll
        for (int m = 0; m < 4; ++m) {
            const int gm0 = bm * FBM + wm + m * 16 + fq * 4;
            #pragma unroll
            for (int j = 0; j < 4; ++j)
                C[(size_t)(gm0 + j) * N_DIM + gn] = acc[m][n][j] * s;
        }
    }
}

extern "C" void kernel_launch(void* const* d_in, const int* in_sizes, int n_in,
                              void* d_out, int out_size, void* d_ws, size_t ws_size,
                              hipStream_t stream) {
    const float* x  = (const float*)d_in[0];
    const int*   w  = (const int*)d_in[1];
    const float* sc = (const float*)d_in[2];
    float* out = (float*)d_out;

    const size_t w_elems = (size_t)N_DIM * K_DIM;
    const size_t x_elems = (size_t)M_DIM * K_DIM;
    const size_t need = (w_elems + x_elems) * sizeof(short);

    if (ws_size >= need) {
        short* wb = (short*)d_ws;
        short* xb = wb + w_elems;
        convert_w<<<dim3(2048), dim3(256), 0, stream>>>(w, wb, (int)(w_elems / 4));
        convert_x<<<dim3(2048), dim3(256), 0, stream>>>(x, xb, (int)(x_elems / 4));
        const int nblocks = (M_DIM / BM) * (N_DIM / BN);  // 32 * 43 = 1376
        gemm_bf16_8ph<<<dim3(nblocks), dim3(512), 0, stream>>>(xb, wb, sc, out);
    } else {
        const int nblocks = (M_DIM / FBM) * (N_DIM / FBN);
        int8_linear_fused<<<dim3(nblocks), dim3(256), 0, stream>>>(x, w, sc, out);
    }
}

// Round 5
// 425.177 us; speedup vs baseline: 4.1242x; 1.6954x over previous
//
#include <hip/hip_runtime.h>
#include <hip/hip_bf16.h>

// Int8Linear: out[M,N] = (x[M,K] fp32) x (w[N,K] int8-in-int32)^T * scale[N]
// Round 5: i8 MFMA path (2x bf16 rate, half the LDS/HBM traffic).
//   prepass: per-row quantize x -> int8 (sx[row] = rowmax/127); pack w -> int8.
//   GEMM: 256x256, BK=128 int8 (same 128-B-row byte geometry & schedule as the
//   proven r4 bf16 kernel), mfma_i32_16x16x64_i8, epilogue * sx[m] * scale[o].

#define M_DIM 8192
#define N_DIM 11008
#define K_DIM 4096

#define BM 256
#define BN 256
#define BK 128   // int8 elems -> 128 B per LDS row, 32 K-tiles

using f32x4 = __attribute__((ext_vector_type(4))) float;
using i32x4 = __attribute__((ext_vector_type(4))) int;
using s16x4 = __attribute__((ext_vector_type(4))) short;
using s16x8 = __attribute__((ext_vector_type(8))) short;

typedef __attribute__((address_space(3))) void lds_void_t;
typedef __attribute__((address_space(1))) const void gbl_void_t;

__device__ __forceinline__ short cvt_bf16(float f) {
    union { float f; unsigned u; } v; v.f = f;
    unsigned r = v.u + 0x7fffu + ((v.u >> 16) & 1u);  // RNE
    return (short)(r >> 16);
}

// ---- prepass: per-row symmetric int8 quantization of x ----
__global__ __launch_bounds__(256) void quant_x(const float* __restrict__ X,
                                               signed char* __restrict__ Q,
                                               float* __restrict__ sx) {
    const int row = blockIdx.x;
    const int tid = threadIdx.x;
    const f32x4* xr = (const f32x4*)(X + (size_t)row * K_DIM);

    f32x4 v[4];
    float m = 0.f;
    #pragma unroll
    for (int i = 0; i < 4; ++i) {
        v[i] = xr[tid * 4 + i];
        #pragma unroll
        for (int j = 0; j < 4; ++j) m = fmaxf(m, fabsf(v[i][j]));
    }
    #pragma unroll
    for (int off = 32; off; off >>= 1) m = fmaxf(m, __shfl_xor(m, off));
    __shared__ float wmax[4];
    if ((tid & 63) == 0) wmax[tid >> 6] = m;
    __syncthreads();
    m = fmaxf(fmaxf(wmax[0], wmax[1]), fmaxf(wmax[2], wmax[3]));

    const float inv = (m > 0.f) ? 127.0f / m : 0.f;
    i32x4 o;
    #pragma unroll
    for (int i = 0; i < 4; ++i) {
        int b0 = __float2int_rn(v[i][0] * inv) & 255;
        int b1 = __float2int_rn(v[i][1] * inv) & 255;
        int b2 = __float2int_rn(v[i][2] * inv) & 255;
        int b3 = __float2int_rn(v[i][3] * inv) & 255;
        o[i] = b0 | (b1 << 8) | (b2 << 16) | (b3 << 24);
    }
    ((i32x4*)(Q + (size_t)row * K_DIM))[tid] = o;
    if (tid == 0) sx[row] = (m > 0.f) ? m * (1.0f / 127.0f) : 0.f;
}

// ---- prepass: int32 weights -> packed int8 (exact) ----
__global__ __launch_bounds__(256) void convert_w(const int* __restrict__ W,
                                                 signed char* __restrict__ Q, int n16) {
    int i = blockIdx.x * blockDim.x + threadIdx.x;
    const int stride = gridDim.x * blockDim.x;
    for (; i < n16; i += stride) {
        i32x4 o;
        #pragma unroll
        for (int j = 0; j < 4; ++j) {
            i32x4 v = ((const i32x4*)W)[i * 4 + j];
            o[j] = (v[0] & 255) | ((v[1] & 255) << 8) | ((v[2] & 255) << 16) | (v[3] << 24);
        }
        ((i32x4*)Q)[i] = o;
    }
}

#define SBAR __builtin_amdgcn_s_barrier()
#define LGKM(n) do { asm volatile("s_waitcnt lgkmcnt(" #n ")" ::: "memory"); \
                     __builtin_amdgcn_sched_barrier(0); } while (0)
#define WAIT_VM(n) do { asm volatile("s_waitcnt vmcnt(" #n ")" ::: "memory"); \
                        __builtin_amdgcn_sched_barrier(0); } while (0)

// Stage one operand tile (256 rows x 128 B = 32 KB): 4 gload_lds x 512 thr x 16 B.
// LDS dest LINEAR; bank swizzle via pre-swizzled global source chunk (jl).
#define STAGE(bufi, opi, srcp, T) do {                                             \
    signed char* _d = &lds[bufi][opi][0];                                          \
    const size_t _toff = (size_t)((T) & 31) * 128;                                 \
    _Pragma("unroll")                                                              \
    for (int _i = 0; _i < 4; ++_i)                                                 \
        __builtin_amdgcn_global_load_lds(                                          \
            (gbl_void_t*)((srcp) + (size_t)_i * 64 * K_DIM + _toff),               \
            (lds_void_t*)(_d + (_i * 512 + tid) * 16), 16, 0, 0);                  \
} while (0)

// Read A quadrant qm: 4 m-frags x 2 k-steps = 8 x ds_read_b128, swizzled.
// byte = row*128 + ((chunk ^ (row&7))*16), chunk = ks*4 + fq, row&7 == fr&7.
#define READ_A(dst, bufi, qm) do {                                                 \
    const signed char* _s = &lds[bufi][0][0];                                      \
    _Pragma("unroll")                                                              \
    for (int _m = 0; _m < 4; ++_m)                                                 \
        _Pragma("unroll")                                                          \
        for (int _k = 0; _k < 2; ++_k)                                             \
            dst[_m][_k] = *(const i32x4*)(_s                                       \
                + (size_t)((mi * 128 + (qm) * 64 + _m * 16 + fr) * 128)            \
                + ((((_k << 2) | fq) ^ fr7) << 4));                                \
} while (0)

// Read B quadrant qn: 2 n-frags x 2 k-steps = 4 x ds_read_b128, swizzled.
#define READ_B(dst, bufi, qn) do {                                                 \
    const signed char* _s = &lds[bufi][1][0];                                      \
    _Pragma("unroll")                                                              \
    for (int _n = 0; _n < 2; ++_n)                                                 \
        _Pragma("unroll")                                                          \
        for (int _k = 0; _k < 2; ++_k)                                             \
            dst[_n][_k] = *(const i32x4*)(_s                                       \
                + (size_t)((ni * 64 + (qn) * 32 + _n * 16 + fr) * 128)             \
                + ((((_k << 2) | fq) ^ fr7) << 4));                                \
} while (0)

#define MFMA_Q(qm, qn, aset, bset) do {                                            \
    __builtin_amdgcn_s_setprio(1);                                                 \
    _Pragma("unroll")                                                              \
    for (int _m = 0; _m < 4; ++_m)                                                 \
        _Pragma("unroll")                                                          \
        for (int _n = 0; _n < 2; ++_n)                                             \
            _Pragma("unroll")                                                      \
            for (int _k = 0; _k < 2; ++_k)                                         \
                acc[(qm) * 4 + _m][(qn) * 2 + _n] =                                \
                    __builtin_amdgcn_mfma_i32_16x16x64_i8(                         \
                        aset[_m][_k], bset[_n][_k],                                \
                        acc[(qm) * 4 + _m][(qn) * 2 + _n], 0, 0, 0);               \
    __builtin_amdgcn_s_setprio(0);                                                 \
} while (0)

// Identical schedule to the verified round-4 kernel (same read/stage counts):
// p1: rB(4)  LGKM(4)  q00 | p2: rA(8) LGKM(8) q01 | p3: stB LGKM(0) q11 VM(4)
// | p4: stA rA(8) rB(4) LGKM(12) q10.  Stages 4-phase-ahead of consumption.
#define HALF_ITER(BUF, OBUF, BQ0, BQ1, T) do {                                     \
    READ_B(BQ1, BUF, 1);                                                           \
    LGKM(4);                                                                       \
    MFMA_Q(0, 0, a0, BQ0);                                                         \
    SBAR;                                                                          \
    READ_A(a1, BUF, 1);                                                            \
    LGKM(8);                                                                       \
    MFMA_Q(0, 1, a0, BQ1);                                                         \
    SBAR;                                                                          \
    STAGE(BUF, 1, Bsrc, (T) + 2);                                                  \
    LGKM(0);                                                                       \
    MFMA_Q(1, 1, a1, BQ1);                                                         \
    WAIT_VM(4);                                                                    \
    SBAR;                                                                          \
    STAGE(BUF, 0, Asrc, (T) + 2);                                                  \
    READ_A(a0, OBUF, 0);                                                           \
    READ_B(BQ1, OBUF, 0);                                                          \
    LGKM(12);                                                                      \
    MFMA_Q(1, 0, a1, BQ0);                                                         \
    SBAR;                                                                          \
} while (0)

__global__ __launch_bounds__(512, 2) void gemm_i8(
    const signed char* __restrict__ A,   // [M, K] int8 (quantized x)
    const signed char* __restrict__ B,   // [N, K] int8 (weights)
    const float* __restrict__ sx,        // [M] row scales of x
    const float* __restrict__ scale,     // [N] channel scales of w
    float*       __restrict__ C)         // [M, N]
{
    __shared__ __align__(16) signed char lds[2][2][256 * 128];  // 128 KiB

    const int tid  = threadIdx.x;
    const int lane = tid & 63;
    const int fr   = lane & 15;
    const int fq   = lane >> 4;
    const int fr7  = fr & 7;
    const int wave = tid >> 6;
    const int mi   = wave >> 2;   // 0..1: A half (128-row block)
    const int ni   = wave & 3;    // 0..3: 64-col block

    // XCD-chunked bijective swizzle: 1376 = 8 x 172; per XCD: 4 bm x 43 bn.
    const int bid = blockIdx.x;
    const int xcd = bid & 7;
    const int idx = bid >> 3;
    const int bm  = xcd * 4 + (idx & 3);  // 0..31
    const int bn  = idx >> 2;             // 0..42

    // Pre-swizzled staging source: chunk c = i*512+tid -> row = i*64+(tid>>3),
    // src chunk = (tid&7) ^ (row&7) = (tid&7) ^ ((tid>>3)&7).  (bytes)
    const int jl   = (tid & 7) ^ ((tid >> 3) & 7);
    const int soff = (tid >> 3) * K_DIM + jl * 16;
    const signed char* Asrc = A + (size_t)bm * BM * K_DIM + soff;
    const signed char* Bsrc = B + (size_t)bn * BN * K_DIM + soff;

    i32x4 acc[8][4] = {};
    i32x4 a0[4][2], a1[4][2], b_a[2][2], b_b[2][2];

    STAGE(0, 1, Bsrc, 0);
    STAGE(0, 0, Asrc, 0);
    STAGE(1, 1, Bsrc, 1);
    STAGE(1, 0, Asrc, 1);
    WAIT_VM(8);
    SBAR;
    READ_A(a0, 0, 0);
    READ_B(b_a, 0, 0);

    for (int it = 0; it < 16; ++it) {
        const int t0 = 2 * it;
        HALF_ITER(0, 1, b_a, b_b, t0);      // tile t0   (buf0)
        HALF_ITER(1, 0, b_b, b_a, t0 + 1);  // tile t0+1 (buf1)
    }

    // Epilogue: out = (float)acc * sx[row] * scale[col], nontemporal stores.
    const int row0 = bm * BM + mi * 128 + fq * 4;
    const int col0 = bn * BN + ni * 64 + fr;
    float s4[4];
    #pragma unroll
    for (int jn = 0; jn < 4; ++jn) s4[jn] = scale[col0 + jn * 16];
    #pragma unroll
    for (int i = 0; i < 8; ++i) {
        float sxv[4];
        #pragma unroll
        for (int jj = 0; jj < 4; ++jj) sxv[jj] = sx[row0 + i * 16 + jj];
        #pragma unroll
        for (int jn = 0; jn < 4; ++jn)
            #pragma unroll
            for (int jj = 0; jj < 4; ++jj)
                __builtin_nontemporal_store(
                    (float)acc[i][jn][jj] * sxv[jj] * s4[jn],
                    &C[(size_t)(row0 + i * 16 + jj) * N_DIM + col0 + jn * 16]);
    }
}

// ---- fallback (round-1 fused bf16 kernel) if ws is too small ----
#define FBM 128
#define FBN 128
#define FBK 32
#define LDK 40
__global__ __launch_bounds__(256) void int8_linear_fused(
    const float* __restrict__ A, const int* __restrict__ W,
    const float* __restrict__ scale, float* __restrict__ C)
{
    __shared__ short As[FBM][LDK];
    __shared__ short Bs[FBN][LDK];
    const int tid = threadIdx.x;
    const int bid = blockIdx.x;
    const int g   = bid / (8 * 86);
    const int rem = bid % (8 * 86);
    const int bm  = g * 8 + (rem & 7);
    const int bn  = rem >> 3;
    const int srow = tid >> 3;
    const int skq  = tid & 7;
    const float* Ab = A + (size_t)(bm * FBM + srow) * K_DIM + skq * 4;
    const int*   Wb = W + (size_t)(bn * FBN + srow) * K_DIM + skq * 4;
    const int lane = tid & 63, wave = tid >> 6;
    const int wm = (wave >> 1) * 64, wn = (wave & 1) * 64;
    const int fr = lane & 15, fq = lane >> 4;
    f32x4 acc[4][4] = {};
    f32x4 areg[4]; i32x4 breg[4];
    #pragma unroll
    for (int i = 0; i < 4; ++i) {
        areg[i] = *(const f32x4*)(Ab + (size_t)(i * 32) * K_DIM);
        breg[i] = *(const i32x4*)(Wb + (size_t)(i * 32) * K_DIM);
    }
    const int NT = K_DIM / FBK;
    for (int kt = 0; kt < NT; ++kt) {
        __syncthreads();
        #pragma unroll
        for (int i = 0; i < 4; ++i) {
            s16x4 av, bv;
            #pragma unroll
            for (int j = 0; j < 4; ++j) {
                av[j] = cvt_bf16(areg[i][j]);
                bv[j] = cvt_bf16((float)breg[i][j]);
            }
            *(s16x4*)&As[srow + i * 32][skq * 4] = av;
            *(s16x4*)&Bs[srow + i * 32][skq * 4] = bv;
        }
        __syncthreads();
        if (kt + 1 < NT) {
            const int k0 = (kt + 1) * FBK;
            #pragma unroll
            for (int i = 0; i < 4; ++i) {
                areg[i] = *(const f32x4*)(Ab + (size_t)(i * 32) * K_DIM + k0);
                breg[i] = *(const i32x4*)(Wb + (size_t)(i * 32) * K_DIM + k0);
            }
        }
        s16x8 af[4], bf[4];
        #pragma unroll
        for (int m = 0; m < 4; ++m) af[m] = *(const s16x8*)&As[wm + m * 16 + fr][fq * 8];
        #pragma unroll
        for (int n = 0; n < 4; ++n) bf[n] = *(const s16x8*)&Bs[wn + n * 16 + fr][fq * 8];
        #pragma unroll
        for (int m = 0; m < 4; ++m)
            #pragma unroll
            for (int n = 0; n < 4; ++n)
                acc[m][n] = __builtin_amdgcn_mfma_f32_16x16x32_bf16(af[m], bf[n], acc[m][n], 0, 0, 0);
    }
    #pragma unroll
    for (int n = 0; n < 4; ++n) {
        const int gn = bn * FBN + wn + n * 16 + fr;
        const float s = scale[gn];
        #pragma unroll
        for (int m = 0; m < 4; ++m) {
            const int gm0 = bm * FBM + wm + m * 16 + fq * 4;
            #pragma unroll
            for (int j = 0; j < 4; ++j)
                C[(size_t)(gm0 + j) * N_DIM + gn] = acc[m][n][j] * s;
        }
    }
}

extern "C" void kernel_launch(void* const* d_in, const int* in_sizes, int n_in,
                              void* d_out, int out_size, void* d_ws, size_t ws_size,
                              hipStream_t stream) {
    const float* x  = (const float*)d_in[0];
    const int*   w  = (const int*)d_in[1];
    const float* sc = (const float*)d_in[2];
    float* out = (float*)d_out;

    const size_t w_bytes  = (size_t)N_DIM * K_DIM;            // 45,088,768
    const size_t x_bytes  = (size_t)M_DIM * K_DIM;            // 33,554,432
    const size_t sx_bytes = (size_t)M_DIM * sizeof(float);    // 32 KB
    const size_t need = w_bytes + x_bytes + sx_bytes;

    if (ws_size >= need) {
        signed char* qw = (signed char*)d_ws;
        signed char* qx = qw + w_bytes;
        float* sx = (float*)(qx + x_bytes);
        convert_w<<<dim3(2048), dim3(256), 0, stream>>>(w, qw, (int)(w_bytes / 16));
        quant_x<<<dim3(M_DIM), dim3(256), 0, stream>>>(x, qx, sx);
        const int nblocks = (M_DIM / BM) * (N_DIM / BN);  // 1376
        gemm_i8<<<dim3(nblocks), dim3(512), 0, stream>>>(qx, qw, sx, sc, out);
    } else {
        const int nblocks = (M_DIM / FBM) * (N_DIM / FBN);
        int8_linear_fused<<<dim3(nblocks), dim3(256), 0, stream>>>(x, w, sc, out);
    }
}